// Round 10
// baseline (155.459 us; speedup 1.0000x reference)
//
#include <hip/hip_runtime.h>
#include <math.h>

// fp16-MFMA flash attention (no-max softmax), S=8192, D=128, fp32 in/out.
// R10: main loop reads K/V frags DIRECTLY from global (L2-resident, XCD-pinned
// slice of 512 KB) into registers -- no LDS, no double-buffer, no barriers in
// the loop. R7 shape otherwise: transposed-S fp16 QK^T, dual-S accumulators,
// in-register P transpose via shfl_xor(32), per-slice partial buffers + norm.
// (R9 post-mortem: occupancy was never binding; the LDS pipe was. R8: device
// fences nuke L2. R6/R9: >8 slices -> partial traffic exceeds L2.)

typedef _Float16 f16x8 __attribute__((ext_vector_type(8)));
typedef float    f32x16 __attribute__((ext_vector_type(16)));

constexpr int S_LEN = 8192;
constexpr int D_K   = 128;
constexpr int NSLICE = 8;
constexpr int ITERS  = (S_LEN / NSLICE) / 32;   // 32 tiles per 1024-key slice

// ws: Lpart[8][8192] fp32 (256 KB) | KV frags (4 MB) | Opart[7] x 4 MB
constexpr size_t WS_L_OFF = 0;
constexpr size_t KV_OFF   = 262144;
constexpr size_t PART_OFF = KV_OFF + (size_t)256 * 16384;
constexpr size_t WS_NEED  = PART_OFF + (size_t)7 * S_LEN * D_K * 4;  // ~32.5 MB

#define CSCALE (0.08838834764831845f * 1.44269504088896340736f)

union UH8 { _Float16 h[8]; uint4 q; f16x8 v; };
union UF4 { unsigned u[4]; uint4 q; f16x8 v; };

// ---------------- prep: frag build (+ zero out/ws_l if atomic path) ----------
template <bool ZOUT>
__global__ __launch_bounds__(512) void attn_prep(const float* __restrict__ K,
                                                 const float* __restrict__ V,
                                                 float* __restrict__ out,
                                                 char* __restrict__ ws) {
  const int t = blockIdx.x * 512 + threadIdx.x;
  uint4* KVg = (uint4*)(ws + KV_OFF);
  if (t < 131072) {
    // K frag: lane holds K[key=lane&31][d0..d0+7], d0 = s*16 + (lane>>5)*8
    int kt = t >> 9, idx = t & 511;
    int lane = idx & 63, s = idx >> 6;
    int key = kt * 32 + (lane & 31);
    int d0  = s * 16 + (lane >> 5) * 8;
    const float4* src = (const float4*)(K + (size_t)key * D_K + d0);
    float4 a = src[0], b = src[1];
    float f[8] = {a.x, a.y, a.z, a.w, b.x, b.y, b.z, b.w};
    UH8 h;
    #pragma unroll
    for (int j = 0; j < 8; ++j) h.h[j] = (_Float16)f[j];
    KVg[(size_t)kt * 1024 + idx] = h.q;
  } else if (t < 262144) {
    // V frag: lane holds V[kb..kb+7][d], d = c*32 + (lane&31)
    int g = t - 131072;
    int kt = g >> 9, idx = g & 511;
    int lane = idx & 63, c = (idx >> 6) & 3, kstep = idx >> 8;
    int d  = c * 32 + (lane & 31);
    int kb = kt * 32 + kstep * 16 + (lane >> 5) * 8;
    UH8 h;
    #pragma unroll
    for (int j = 0; j < 8; ++j) h.h[j] = (_Float16)V[(size_t)(kb + j) * D_K + d];
    KVg[(size_t)kt * 1024 + 512 + idx] = h.q;
  } else if (ZOUT && t < 327680) {
    int i = t - 262144;  // zero out: 65536 threads x 4 float4
    float4 z = make_float4(0.f, 0.f, 0.f, 0.f);
    float4* o4 = (float4*)out;
    #pragma unroll
    for (int j = 0; j < 4; ++j) o4[(size_t)i * 4 + j] = z;
  } else if (ZOUT && t < 329728) {
    int i = t - 327680;  // zero ws_l: 2048 float4
    ((float4*)(ws + WS_L_OFF))[i] = make_float4(0.f, 0.f, 0.f, 0.f);
  }
}

// ---------------- main attention kernel (no LDS, no barriers) ----------------
template <bool PARTIAL>
__global__ __launch_bounds__(256, 2)
void attn_main(const float* __restrict__ Qg, float* __restrict__ out,
               char* __restrict__ ws) {
  const int tid   = threadIdx.x;
  const int wave  = tid >> 6;
  const int lane  = tid & 63;
  const int lrow  = lane & 31;
  const int lhalf = lane >> 5;

  const int blk = blockIdx.x;
  const int ks  = blk & 7;               // k-slice (XCD-pinned by dispatch % 8)
  const int qb  = blk >> 3;              // 0..63
  const int qw  = qb * 128 + wave * 32;  // wave's 32-row q base

  float* ws_l = (float*)(ws + WS_L_OFF);

  // ---- Q B-frags: lane holds Q[q=lane&31][d=(lane>>5)*8+j + 16s], scaled ----
  f16x8 qf[8];
  {
    const int q = qw + lrow;
    #pragma unroll
    for (int s = 0; s < 8; ++s) {
      const float4* src = (const float4*)(Qg + (size_t)q * D_K + s * 16 + lhalf * 8);
      float4 a = src[0], b = src[1];
      float f[8] = {a.x, a.y, a.z, a.w, b.x, b.y, b.z, b.w};
      UH8 h;
      #pragma unroll
      for (int j = 0; j < 8; ++j) h.h[j] = (_Float16)(f[j] * CSCALE);
      qf[s] = h.v;
    }
  }

  f32x16 O0{}, O1{}, O2{}, O3{};
  float lsum = 0.f;

  // per-lane base into this slice's frag stream
  const uint4* KVs = (const uint4*)(ws + KV_OFF) + (size_t)(ks * ITERS) * 1024 + lane;

  #pragma unroll 2
  for (int it = 0; it < ITERS; ++it) {
    const uint4* tb = KVs + (size_t)it * 1024;

    // ---- direct L2->reg frag loads: 16 coalesced dwordx4 per lane ----
    uint4 kr[8], vr[8];
    #pragma unroll
    for (int s = 0; s < 8; ++s) kr[s] = tb[s * 64];
    #pragma unroll
    for (int f = 0; f < 8; ++f) vr[f] = tb[512 + f * 64];

    // ---- S^T = K Q^T : dual accumulators, two interleaved 4-deep chains ----
    f32x16 Sa{}, Sb{};
    #pragma unroll
    for (int s = 0; s < 4; ++s) {
      f16x8 ka = __builtin_bit_cast(f16x8, kr[2 * s]);
      f16x8 kb = __builtin_bit_cast(f16x8, kr[2 * s + 1]);
      Sa = __builtin_amdgcn_mfma_f32_32x32x16_f16(ka, qf[2 * s    ], Sa, 0, 0, 0);
      Sb = __builtin_amdgcn_mfma_f32_32x32x16_f16(kb, qf[2 * s + 1], Sb, 0, 0, 0);
    }

    // ---- P^T = exp2(Sa+Sb); per-lane row sums; pack to fp16 pairs ----
    unsigned pk[8];
    #pragma unroll
    for (int i = 0; i < 8; ++i) {
      float p0 = __builtin_amdgcn_exp2f(Sa[2 * i]     + Sb[2 * i]);
      float p1 = __builtin_amdgcn_exp2f(Sa[2 * i + 1] + Sb[2 * i + 1]);
      lsum += p0 + p1;
      pk[i] = __builtin_bit_cast(unsigned, __builtin_amdgcn_cvt_pkrtz(p0, p1));
    }

    // ---- in-register transpose to P A-frags (lane<->lane+32 half swap) ----
    unsigned s0 = __shfl_xor(pk[0], 32), s1 = __shfl_xor(pk[1], 32);
    unsigned s2 = __shfl_xor(pk[2], 32), s3 = __shfl_xor(pk[3], 32);
    unsigned s4 = __shfl_xor(pk[4], 32), s5 = __shfl_xor(pk[5], 32);
    unsigned s6 = __shfl_xor(pk[6], 32), s7 = __shfl_xor(pk[7], 32);
    UF4 A0, A1;
    A0.u[0] = lhalf ? s2 : pk[0];
    A0.u[1] = lhalf ? s3 : pk[1];
    A0.u[2] = lhalf ? pk[2] : s0;
    A0.u[3] = lhalf ? pk[3] : s1;
    A1.u[0] = lhalf ? s6 : pk[4];
    A1.u[1] = lhalf ? s7 : pk[5];
    A1.u[2] = lhalf ? pk[6] : s4;
    A1.u[3] = lhalf ? pk[7] : s5;

    // ---- O += P V : 8 MFMAs, 4 independent chains ----
    #pragma unroll
    for (int kstep = 0; kstep < 2; ++kstep) {
      f16x8 pf = kstep ? A1.v : A0.v;
      O0 = __builtin_amdgcn_mfma_f32_32x32x16_f16(pf, __builtin_bit_cast(f16x8, vr[kstep * 4 + 0]), O0, 0, 0, 0);
      O1 = __builtin_amdgcn_mfma_f32_32x32x16_f16(pf, __builtin_bit_cast(f16x8, vr[kstep * 4 + 1]), O1, 0, 0, 0);
      O2 = __builtin_amdgcn_mfma_f32_32x32x16_f16(pf, __builtin_bit_cast(f16x8, vr[kstep * 4 + 2]), O2, 0, 0, 0);
      O3 = __builtin_amdgcn_mfma_f32_32x32x16_f16(pf, __builtin_bit_cast(f16x8, vr[kstep * 4 + 3]), O3, 0, 0, 0);
    }
  }

  // ---- epilogue ----
  lsum += __shfl_xor(lsum, 32);           // combine the two key-halves

  if (PARTIAL) {
    if (lhalf == 0) ws_l[ks * S_LEN + qw + lrow] = lsum;   // plain store
    float* obase = (ks == 0) ? out
                 : (float*)(ws + PART_OFF) + (size_t)(ks - 1) * S_LEN * D_K;
    #pragma unroll
    for (int r = 0; r < 16; ++r) {
      int row = (r & 3) + 8 * (r >> 2) + 4 * lhalf;
      float* dst = obase + (size_t)(qw + row) * D_K + lrow;
      dst[ 0] = O0[r];
      dst[32] = O1[r];
      dst[64] = O2[r];
      dst[96] = O3[r];
    }
  } else {
    if (lhalf == 0) atomicAdd(ws_l + qw + lrow, lsum);
    #pragma unroll
    for (int r = 0; r < 16; ++r) {
      int row = (r & 3) + 8 * (r >> 2) + 4 * lhalf;
      float* dst = out + (size_t)(qw + row) * D_K + lrow;
      atomicAdd(dst +  0, O0[r]);
      atomicAdd(dst + 32, O1[r]);
      atomicAdd(dst + 64, O2[r]);
      atomicAdd(dst + 96, O3[r]);
    }
  }
}

// ---------------- reduce partials (nparts>0) or just normalize (nparts=0) ----
__global__ __launch_bounds__(256) void attn_norm(float* __restrict__ out,
                                                 const float* __restrict__ lpart,
                                                 const float* __restrict__ opart,
                                                 int nparts) {
  int i = blockIdx.x * 256 + threadIdx.x;  // float4 index, 262144 total
  int q = i >> 5;
  float4* o4 = (float4*)out;
  float4 acc = o4[i];
  float l = lpart[q];
  for (int s = 1; s <= nparts; ++s) {
    float4 p = ((const float4*)opart)[(size_t)(s - 1) * 262144 + i];
    acc.x += p.x; acc.y += p.y; acc.z += p.z; acc.w += p.w;
    l += lpart[s * S_LEN + q];
  }
  float inv = 1.0f / l;
  acc.x *= inv; acc.y *= inv; acc.z *= inv; acc.w *= inv;
  o4[i] = acc;
}

extern "C" void kernel_launch(void* const* d_in, const int* in_sizes, int n_in,
                              void* d_out, int out_size, void* d_ws, size_t ws_size,
                              hipStream_t stream) {
  const float* q = (const float*)d_in[0];
  const float* k = (const float*)d_in[1];
  const float* v = (const float*)d_in[2];
  float* out = (float*)d_out;
  char* ws = (char*)d_ws;

  if (ws_size >= WS_NEED) {
    attn_prep<false><<<dim3(512), dim3(512), 0, stream>>>(k, v, out, ws);
    attn_main<true><<<dim3(512), dim3(256), 0, stream>>>(q, out, ws);
    attn_norm<<<dim3(1024), dim3(256), 0, stream>>>(
        out, (const float*)(ws + WS_L_OFF), (const float*)(ws + PART_OFF), 7);
  } else {
    attn_prep<true><<<dim3(645), dim3(512), 0, stream>>>(k, v, out, ws);
    attn_main<false><<<dim3(512), dim3(256), 0, stream>>>(q, out, ws);
    attn_norm<<<dim3(1024), dim3(256), 0, stream>>>(
        out, (const float*)(ws + WS_L_OFF), (const float*)(ws + PART_OFF), 0);
  }
}

// Round 12
// 113.348 us; speedup vs baseline: 1.3715x; 1.3715x over previous
//
#include <hip/hip_runtime.h>
#include <math.h>

// fp16-MFMA flash attention (no-max softmax), S=8192, D=128, fp32 in/out.
// R12 = R7 (the 114 us champion) with ONE change: 64-key double buffers ->
// 16 barriers instead of 32 (each drain amortized over 2x compute).
// Core: transposed-S fp16 QK^T (A=K, B=Q), dual-S accumulators, in-register
// P transpose via shfl_xor(32), async global_load_lds staging, per-slice
// partial-store epilogue + separate reduce/norm kernel. 3 dispatches.
// Graveyard: R8/R11 fusion (fences/coop-launch), R9 16-slice (partials
// spill L2), R10 direct L2->reg (latency, no broadcast), R4 64q/wave (occ).

typedef _Float16 f16x8 __attribute__((ext_vector_type(8)));
typedef float    f32x16 __attribute__((ext_vector_type(16)));

constexpr int S_LEN = 8192;
constexpr int D_K   = 128;
constexpr int NSLICE = 8;
constexpr int ITERS2 = (S_LEN / NSLICE) / 64;   // 16 iters of 64 keys

// ws: Lpart[8][8192] fp32 (256 KB) | KV frags (4 MB) | Opart[7] x 4 MB
constexpr size_t WS_L_OFF = 0;
constexpr size_t KV_OFF   = 262144;
constexpr size_t PART_OFF = KV_OFF + (size_t)256 * 16384;
constexpr size_t WS_NEED  = PART_OFF + (size_t)7 * S_LEN * D_K * 4;  // ~32.5 MB

#define CSCALE (0.08838834764831845f * 1.44269504088896340736f)

union UH8 { _Float16 h[8]; uint4 q; f16x8 v; };
union UF4 { unsigned u[4]; uint4 q; f16x8 v; };

__device__ inline void async16(const uint4* g, uint4* l) {
  __builtin_amdgcn_global_load_lds(
      (const __attribute__((address_space(1))) unsigned int*)g,
      (__attribute__((address_space(3))) unsigned int*)l, 16, 0, 0);
}

// ---------------- prep: frag build (+ zero out/ws_l if atomic path) ----------
template <bool ZOUT>
__global__ __launch_bounds__(512) void attn_prep(const float* __restrict__ K,
                                                 const float* __restrict__ V,
                                                 float* __restrict__ out,
                                                 char* __restrict__ ws) {
  const int t = blockIdx.x * 512 + threadIdx.x;
  uint4* KVg = (uint4*)(ws + KV_OFF);
  if (t < 131072) {
    // K frag: lane holds K[key=lane&31][d0..d0+7], d0 = s*16 + (lane>>5)*8
    int kt = t >> 9, idx = t & 511;
    int lane = idx & 63, s = idx >> 6;
    int key = kt * 32 + (lane & 31);
    int d0  = s * 16 + (lane >> 5) * 8;
    const float4* src = (const float4*)(K + (size_t)key * D_K + d0);
    float4 a = src[0], b = src[1];
    float f[8] = {a.x, a.y, a.z, a.w, b.x, b.y, b.z, b.w};
    UH8 h;
    #pragma unroll
    for (int j = 0; j < 8; ++j) h.h[j] = (_Float16)f[j];
    KVg[(size_t)kt * 1024 + idx] = h.q;
  } else if (t < 262144) {
    // V frag: lane holds V[kb..kb+7][d], d = c*32 + (lane&31)
    int g = t - 131072;
    int kt = g >> 9, idx = g & 511;
    int lane = idx & 63, c = (idx >> 6) & 3, kstep = idx >> 8;
    int d  = c * 32 + (lane & 31);
    int kb = kt * 32 + kstep * 16 + (lane >> 5) * 8;
    UH8 h;
    #pragma unroll
    for (int j = 0; j < 8; ++j) h.h[j] = (_Float16)V[(size_t)(kb + j) * D_K + d];
    KVg[(size_t)kt * 1024 + 512 + idx] = h.q;
  } else if (ZOUT && t < 327680) {
    int i = t - 262144;  // zero out: 65536 threads x 4 float4
    float4 z = make_float4(0.f, 0.f, 0.f, 0.f);
    float4* o4 = (float4*)out;
    #pragma unroll
    for (int j = 0; j < 4; ++j) o4[(size_t)i * 4 + j] = z;
  } else if (ZOUT && t < 329728) {
    int i = t - 327680;  // zero ws_l: 2048 float4
    ((float4*)(ws + WS_L_OFF))[i] = make_float4(0.f, 0.f, 0.f, 0.f);
  }
}

// ---------------- main attention kernel ----------------
template <bool PARTIAL>
__global__ __launch_bounds__(256, 2)
void attn_main(const float* __restrict__ Qg, float* __restrict__ out,
               char* __restrict__ ws) {
  __shared__ uint4 KV[2][2048];   // dbuf of 64-key pairs: [K|V][K|V]

  const int tid   = threadIdx.x;
  const int wave  = tid >> 6;
  const int lane  = tid & 63;
  const int lrow  = lane & 31;
  const int lhalf = lane >> 5;

  const int blk = blockIdx.x;
  const int ks  = blk & 7;               // k-slice (XCD-pinned by dispatch % 8)
  const int qb  = blk >> 3;              // 0..63
  const int qw  = qb * 128 + wave * 32;  // wave's 32-row q base

  float* ws_l = (float*)(ws + WS_L_OFF);

  // ---- Q B-frags: lane holds Q[q=lane&31][d=(lane>>5)*8+j + 16s], scaled ----
  f16x8 qf[8];
  {
    const int q = qw + lrow;
    #pragma unroll
    for (int s = 0; s < 8; ++s) {
      const float4* src = (const float4*)(Qg + (size_t)q * D_K + s * 16 + lhalf * 8);
      float4 a = src[0], b = src[1];
      float f[8] = {a.x, a.y, a.z, a.w, b.x, b.y, b.z, b.w};
      UH8 h;
      #pragma unroll
      for (int j = 0; j < 8; ++j) h.h[j] = (_Float16)(f[j] * CSCALE);
      qf[s] = h.v;
    }
  }

  f32x16 O0{}, O1{}, O2{}, O3{};
  float lsum = 0.f;

  const uint4* KVg = (const uint4*)(ws + KV_OFF);

  // prologue: stage 64-key pair 0 (32 KB, 8 async16/thread)
  {
    const size_t base = (size_t)ks * 32768;
    #pragma unroll
    for (int i = 0; i < 8; ++i)
      async16(KVg + base + i * 256 + tid, &KV[0][i * 256 + tid]);
  }

  for (int it = 0; it < ITERS2; ++it) {
    const int buf = it & 1;
    __syncthreads();   // drains async loads -> KV[buf] ready (16 barriers total)

    if (it + 1 < ITERS2) {
      const size_t base = (size_t)ks * 32768 + (size_t)(it + 1) * 2048;
      #pragma unroll
      for (int i = 0; i < 8; ++i)
        async16(KVg + base + i * 256 + tid, &KV[buf ^ 1][i * 256 + tid]);
    }

    #pragma unroll
    for (int u = 0; u < 2; ++u) {
      const uint4* sub = &KV[buf][u * 1024];

      // ---- S^T = K Q^T : dual accumulators, two interleaved 4-deep chains ----
      f32x16 Sa{}, Sb{};
      #pragma unroll
      for (int s = 0; s < 4; ++s) {
        f16x8 ka = __builtin_bit_cast(f16x8, sub[(2 * s    ) * 64 + lane]);
        f16x8 kb = __builtin_bit_cast(f16x8, sub[(2 * s + 1) * 64 + lane]);
        Sa = __builtin_amdgcn_mfma_f32_32x32x16_f16(ka, qf[2 * s    ], Sa, 0, 0, 0);
        Sb = __builtin_amdgcn_mfma_f32_32x32x16_f16(kb, qf[2 * s + 1], Sb, 0, 0, 0);
      }

      // ---- P^T = exp2(Sa+Sb); per-lane row sums; pack to fp16 pairs ----
      unsigned pk[8];
      #pragma unroll
      for (int i = 0; i < 8; ++i) {
        float p0 = __builtin_amdgcn_exp2f(Sa[2 * i]     + Sb[2 * i]);
        float p1 = __builtin_amdgcn_exp2f(Sa[2 * i + 1] + Sb[2 * i + 1]);
        lsum += p0 + p1;
        pk[i] = __builtin_bit_cast(unsigned, __builtin_amdgcn_cvt_pkrtz(p0, p1));
      }

      // ---- in-register transpose to P A-frags (lane<->lane+32 half swap) ----
      unsigned s0 = __shfl_xor(pk[0], 32), s1 = __shfl_xor(pk[1], 32);
      unsigned s2 = __shfl_xor(pk[2], 32), s3 = __shfl_xor(pk[3], 32);
      unsigned s4 = __shfl_xor(pk[4], 32), s5 = __shfl_xor(pk[5], 32);
      unsigned s6 = __shfl_xor(pk[6], 32), s7 = __shfl_xor(pk[7], 32);
      UF4 A0, A1;
      A0.u[0] = lhalf ? s2 : pk[0];
      A0.u[1] = lhalf ? s3 : pk[1];
      A0.u[2] = lhalf ? pk[2] : s0;
      A0.u[3] = lhalf ? pk[3] : s1;
      A1.u[0] = lhalf ? s6 : pk[4];
      A1.u[1] = lhalf ? s7 : pk[5];
      A1.u[2] = lhalf ? pk[6] : s4;
      A1.u[3] = lhalf ? pk[7] : s5;

      // ---- O += P V : 8 MFMAs, 4 independent chains ----
      #pragma unroll
      for (int kstep = 0; kstep < 2; ++kstep) {
        f16x8 pf = kstep ? A1.v : A0.v;
        f16x8 v0 = __builtin_bit_cast(f16x8, sub[512 + kstep * 256 +   0 + lane]);
        f16x8 v1 = __builtin_bit_cast(f16x8, sub[512 + kstep * 256 +  64 + lane]);
        f16x8 v2 = __builtin_bit_cast(f16x8, sub[512 + kstep * 256 + 128 + lane]);
        f16x8 v3 = __builtin_bit_cast(f16x8, sub[512 + kstep * 256 + 192 + lane]);
        O0 = __builtin_amdgcn_mfma_f32_32x32x16_f16(pf, v0, O0, 0, 0, 0);
        O1 = __builtin_amdgcn_mfma_f32_32x32x16_f16(pf, v1, O1, 0, 0, 0);
        O2 = __builtin_amdgcn_mfma_f32_32x32x16_f16(pf, v2, O2, 0, 0, 0);
        O3 = __builtin_amdgcn_mfma_f32_32x32x16_f16(pf, v3, O3, 0, 0, 0);
      }
    }
  }

  // ---- epilogue ----
  lsum += __shfl_xor(lsum, 32);           // combine the two key-halves

  if (PARTIAL) {
    if (lhalf == 0) ws_l[ks * S_LEN + qw + lrow] = lsum;   // plain store
    float* obase = (ks == 0) ? out
                 : (float*)(ws + PART_OFF) + (size_t)(ks - 1) * S_LEN * D_K;
    #pragma unroll
    for (int r = 0; r < 16; ++r) {
      int row = (r & 3) + 8 * (r >> 2) + 4 * lhalf;
      float* dst = obase + (size_t)(qw + row) * D_K + lrow;
      dst[ 0] = O0[r];
      dst[32] = O1[r];
      dst[64] = O2[r];
      dst[96] = O3[r];
    }
  } else {
    if (lhalf == 0) atomicAdd(ws_l + qw + lrow, lsum);
    #pragma unroll
    for (int r = 0; r < 16; ++r) {
      int row = (r & 3) + 8 * (r >> 2) + 4 * lhalf;
      float* dst = out + (size_t)(qw + row) * D_K + lrow;
      atomicAdd(dst +  0, O0[r]);
      atomicAdd(dst + 32, O1[r]);
      atomicAdd(dst + 64, O2[r]);
      atomicAdd(dst + 96, O3[r]);
    }
  }
}

// ---------------- reduce partials (nparts>0) or just normalize (nparts=0) ----
__global__ __launch_bounds__(256) void attn_norm(float* __restrict__ out,
                                                 const float* __restrict__ lpart,
                                                 const float* __restrict__ opart,
                                                 int nparts) {
  int i = blockIdx.x * 256 + threadIdx.x;  // float4 index, 262144 total
  int q = i >> 5;
  float4* o4 = (float4*)out;
  float4 acc = o4[i];
  float l = lpart[q];
  for (int s = 1; s <= nparts; ++s) {
    float4 p = ((const float4*)opart)[(size_t)(s - 1) * 262144 + i];
    acc.x += p.x; acc.y += p.y; acc.z += p.z; acc.w += p.w;
    l += lpart[s * S_LEN + q];
  }
  float inv = 1.0f / l;
  acc.x *= inv; acc.y *= inv; acc.z *= inv; acc.w *= inv;
  o4[i] = acc;
}

extern "C" void kernel_launch(void* const* d_in, const int* in_sizes, int n_in,
                              void* d_out, int out_size, void* d_ws, size_t ws_size,
                              hipStream_t stream) {
  const float* q = (const float*)d_in[0];
  const float* k = (const float*)d_in[1];
  const float* v = (const float*)d_in[2];
  float* out = (float*)d_out;
  char* ws = (char*)d_ws;

  if (ws_size >= WS_NEED) {
    attn_prep<false><<<dim3(512), dim3(512), 0, stream>>>(k, v, out, ws);
    attn_main<true><<<dim3(512), dim3(256), 0, stream>>>(q, out, ws);
    attn_norm<<<dim3(1024), dim3(256), 0, stream>>>(
        out, (const float*)(ws + WS_L_OFF), (const float*)(ws + PART_OFF), 7);
  } else {
    attn_prep<true><<<dim3(645), dim3(512), 0, stream>>>(k, v, out, ws);
    attn_main<false><<<dim3(512), dim3(256), 0, stream>>>(q, out, ws);
    attn_norm<<<dim3(1024), dim3(256), 0, stream>>>(
        out, (const float*)(ws + WS_L_OFF), (const float*)(ws + PART_OFF), 0);
  }
}

// Round 13
// 112.614 us; speedup vs baseline: 1.3805x; 1.0065x over previous
//
#include <hip/hip_runtime.h>
#include <math.h>

// fp16-MFMA flash attention (no-max softmax), S=8192, D=128, fp32 in/out.
// R13 = R12 with the K-loop software-pipelined: both subtiles' QK^T MFMAs
// issued before either softmax, so QK(1) executes under softmax(0) VALU and
// PV(0) under softmax(1) (in-order wave => program-order issue overlaps
// long-latency MFMA pipes). +48 VGPR for in-flight S; still 2 waves/SIMD.
// Core unchanged: transposed-S fp16 QK^T (A=K,B=Q), dual-S accumulators,
// in-register P transpose via shfl_xor(32), async global_load_lds 64-key
// dbuf (16 barriers), per-slice partial stores + reduce/norm kernel.
// Graveyard: R8/R11 fusion, R9 16-slice fp32 partials, R10 direct L2->reg,
// R4 64q/wave, R6 16-slice atomics.

typedef _Float16 f16x8 __attribute__((ext_vector_type(8)));
typedef float    f32x16 __attribute__((ext_vector_type(16)));

constexpr int S_LEN = 8192;
constexpr int D_K   = 128;
constexpr int NSLICE = 8;
constexpr int ITERS2 = (S_LEN / NSLICE) / 64;   // 16 iters of 64 keys

// ws: Lpart[8][8192] fp32 (256 KB) | KV frags (4 MB) | Opart[7] x 4 MB
constexpr size_t WS_L_OFF = 0;
constexpr size_t KV_OFF   = 262144;
constexpr size_t PART_OFF = KV_OFF + (size_t)256 * 16384;
constexpr size_t WS_NEED  = PART_OFF + (size_t)7 * S_LEN * D_K * 4;  // ~32.5 MB

#define CSCALE (0.08838834764831845f * 1.44269504088896340736f)

union UH8 { _Float16 h[8]; uint4 q; f16x8 v; };
union UF4 { unsigned u[4]; uint4 q; f16x8 v; };

__device__ inline void async16(const uint4* g, uint4* l) {
  __builtin_amdgcn_global_load_lds(
      (const __attribute__((address_space(1))) unsigned int*)g,
      (__attribute__((address_space(3))) unsigned int*)l, 16, 0, 0);
}

// ---------------- prep: frag build (+ zero out/ws_l if atomic path) ----------
template <bool ZOUT>
__global__ __launch_bounds__(512) void attn_prep(const float* __restrict__ K,
                                                 const float* __restrict__ V,
                                                 float* __restrict__ out,
                                                 char* __restrict__ ws) {
  const int t = blockIdx.x * 512 + threadIdx.x;
  uint4* KVg = (uint4*)(ws + KV_OFF);
  if (t < 131072) {
    // K frag: lane holds K[key=lane&31][d0..d0+7], d0 = s*16 + (lane>>5)*8
    int kt = t >> 9, idx = t & 511;
    int lane = idx & 63, s = idx >> 6;
    int key = kt * 32 + (lane & 31);
    int d0  = s * 16 + (lane >> 5) * 8;
    const float4* src = (const float4*)(K + (size_t)key * D_K + d0);
    float4 a = src[0], b = src[1];
    float f[8] = {a.x, a.y, a.z, a.w, b.x, b.y, b.z, b.w};
    UH8 h;
    #pragma unroll
    for (int j = 0; j < 8; ++j) h.h[j] = (_Float16)f[j];
    KVg[(size_t)kt * 1024 + idx] = h.q;
  } else if (t < 262144) {
    // V frag: lane holds V[kb..kb+7][d], d = c*32 + (lane&31)
    int g = t - 131072;
    int kt = g >> 9, idx = g & 511;
    int lane = idx & 63, c = (idx >> 6) & 3, kstep = idx >> 8;
    int d  = c * 32 + (lane & 31);
    int kb = kt * 32 + kstep * 16 + (lane >> 5) * 8;
    UH8 h;
    #pragma unroll
    for (int j = 0; j < 8; ++j) h.h[j] = (_Float16)V[(size_t)(kb + j) * D_K + d];
    KVg[(size_t)kt * 1024 + 512 + idx] = h.q;
  } else if (ZOUT && t < 327680) {
    int i = t - 262144;  // zero out: 65536 threads x 4 float4
    float4 z = make_float4(0.f, 0.f, 0.f, 0.f);
    float4* o4 = (float4*)out;
    #pragma unroll
    for (int j = 0; j < 4; ++j) o4[(size_t)i * 4 + j] = z;
  } else if (ZOUT && t < 329728) {
    int i = t - 327680;  // zero ws_l: 2048 float4
    ((float4*)(ws + WS_L_OFF))[i] = make_float4(0.f, 0.f, 0.f, 0.f);
  }
}

// ---------------- main attention kernel ----------------
template <bool PARTIAL>
__global__ __launch_bounds__(256, 2)
void attn_main(const float* __restrict__ Qg, float* __restrict__ out,
               char* __restrict__ ws) {
  __shared__ uint4 KV[2][2048];   // dbuf of 64-key pairs: [K|V][K|V]

  const int tid   = threadIdx.x;
  const int wave  = tid >> 6;
  const int lane  = tid & 63;
  const int lrow  = lane & 31;
  const int lhalf = lane >> 5;

  const int blk = blockIdx.x;
  const int ks  = blk & 7;               // k-slice (XCD-pinned by dispatch % 8)
  const int qb  = blk >> 3;              // 0..63
  const int qw  = qb * 128 + wave * 32;  // wave's 32-row q base

  float* ws_l = (float*)(ws + WS_L_OFF);

  // ---- Q B-frags: lane holds Q[q=lane&31][d=(lane>>5)*8+j + 16s], scaled ----
  f16x8 qf[8];
  {
    const int q = qw + lrow;
    #pragma unroll
    for (int s = 0; s < 8; ++s) {
      const float4* src = (const float4*)(Qg + (size_t)q * D_K + s * 16 + lhalf * 8);
      float4 a = src[0], b = src[1];
      float f[8] = {a.x, a.y, a.z, a.w, b.x, b.y, b.z, b.w};
      UH8 h;
      #pragma unroll
      for (int j = 0; j < 8; ++j) h.h[j] = (_Float16)(f[j] * CSCALE);
      qf[s] = h.v;
    }
  }

  f32x16 O0{}, O1{}, O2{}, O3{};
  float lsum = 0.f;

  const uint4* KVg = (const uint4*)(ws + KV_OFF);

  // prologue: stage 64-key pair 0 (32 KB, 8 async16/thread)
  {
    const size_t base = (size_t)ks * 32768;
    #pragma unroll
    for (int i = 0; i < 8; ++i)
      async16(KVg + base + i * 256 + tid, &KV[0][i * 256 + tid]);
  }

  for (int it = 0; it < ITERS2; ++it) {
    const int buf = it & 1;
    __syncthreads();   // drains async loads -> KV[buf] ready

    if (it + 1 < ITERS2) {
      const size_t base = (size_t)ks * 32768 + (size_t)(it + 1) * 2048;
      #pragma unroll
      for (int i = 0; i < 8; ++i)
        async16(KVg + base + i * 256 + tid, &KV[buf ^ 1][i * 256 + tid]);
    }

    const uint4* sub0 = &KV[buf][0];
    const uint4* sub1 = &KV[buf][1024];

    // ---- stage A: QK^T for BOTH subtiles (4 independent dual-S chains) ----
    f32x16 Sa0{}, Sb0{}, Sa1{}, Sb1{};
    #pragma unroll
    for (int s = 0; s < 4; ++s) {
      f16x8 ka0 = __builtin_bit_cast(f16x8, sub0[(2 * s    ) * 64 + lane]);
      f16x8 kb0 = __builtin_bit_cast(f16x8, sub0[(2 * s + 1) * 64 + lane]);
      Sa0 = __builtin_amdgcn_mfma_f32_32x32x16_f16(ka0, qf[2 * s    ], Sa0, 0, 0, 0);
      Sb0 = __builtin_amdgcn_mfma_f32_32x32x16_f16(kb0, qf[2 * s + 1], Sb0, 0, 0, 0);
    }
    #pragma unroll
    for (int s = 0; s < 4; ++s) {
      f16x8 ka1 = __builtin_bit_cast(f16x8, sub1[(2 * s    ) * 64 + lane]);
      f16x8 kb1 = __builtin_bit_cast(f16x8, sub1[(2 * s + 1) * 64 + lane]);
      Sa1 = __builtin_amdgcn_mfma_f32_32x32x16_f16(ka1, qf[2 * s    ], Sa1, 0, 0, 0);
      Sb1 = __builtin_amdgcn_mfma_f32_32x32x16_f16(kb1, qf[2 * s + 1], Sb1, 0, 0, 0);
    }

    // ---- stage B: softmax(0) -- VALU overlaps QK(1) MFMA drain ----
    UF4 A00, A01;
    {
      unsigned pk[8];
      #pragma unroll
      for (int i = 0; i < 8; ++i) {
        float p0 = __builtin_amdgcn_exp2f(Sa0[2 * i]     + Sb0[2 * i]);
        float p1 = __builtin_amdgcn_exp2f(Sa0[2 * i + 1] + Sb0[2 * i + 1]);
        lsum += p0 + p1;
        pk[i] = __builtin_bit_cast(unsigned, __builtin_amdgcn_cvt_pkrtz(p0, p1));
      }
      unsigned s0 = __shfl_xor(pk[0], 32), s1 = __shfl_xor(pk[1], 32);
      unsigned s2 = __shfl_xor(pk[2], 32), s3 = __shfl_xor(pk[3], 32);
      unsigned s4 = __shfl_xor(pk[4], 32), s5 = __shfl_xor(pk[5], 32);
      unsigned s6 = __shfl_xor(pk[6], 32), s7 = __shfl_xor(pk[7], 32);
      A00.u[0] = lhalf ? s2 : pk[0];
      A00.u[1] = lhalf ? s3 : pk[1];
      A00.u[2] = lhalf ? pk[2] : s0;
      A00.u[3] = lhalf ? pk[3] : s1;
      A01.u[0] = lhalf ? s6 : pk[4];
      A01.u[1] = lhalf ? s7 : pk[5];
      A01.u[2] = lhalf ? pk[6] : s4;
      A01.u[3] = lhalf ? pk[7] : s5;
    }

    // ---- stage C: PV(0) ----
    #pragma unroll
    for (int kstep = 0; kstep < 2; ++kstep) {
      f16x8 pf = kstep ? A01.v : A00.v;
      f16x8 v0 = __builtin_bit_cast(f16x8, sub0[512 + kstep * 256 +   0 + lane]);
      f16x8 v1 = __builtin_bit_cast(f16x8, sub0[512 + kstep * 256 +  64 + lane]);
      f16x8 v2 = __builtin_bit_cast(f16x8, sub0[512 + kstep * 256 + 128 + lane]);
      f16x8 v3 = __builtin_bit_cast(f16x8, sub0[512 + kstep * 256 + 192 + lane]);
      O0 = __builtin_amdgcn_mfma_f32_32x32x16_f16(pf, v0, O0, 0, 0, 0);
      O1 = __builtin_amdgcn_mfma_f32_32x32x16_f16(pf, v1, O1, 0, 0, 0);
      O2 = __builtin_amdgcn_mfma_f32_32x32x16_f16(pf, v2, O2, 0, 0, 0);
      O3 = __builtin_amdgcn_mfma_f32_32x32x16_f16(pf, v3, O3, 0, 0, 0);
    }

    // ---- stage D: softmax(1) -- VALU overlaps PV(0) MFMA drain ----
    UF4 A10, A11;
    {
      unsigned pk[8];
      #pragma unroll
      for (int i = 0; i < 8; ++i) {
        float p0 = __builtin_amdgcn_exp2f(Sa1[2 * i]     + Sb1[2 * i]);
        float p1 = __builtin_amdgcn_exp2f(Sa1[2 * i + 1] + Sb1[2 * i + 1]);
        lsum += p0 + p1;
        pk[i] = __builtin_bit_cast(unsigned, __builtin_amdgcn_cvt_pkrtz(p0, p1));
      }
      unsigned s0 = __shfl_xor(pk[0], 32), s1 = __shfl_xor(pk[1], 32);
      unsigned s2 = __shfl_xor(pk[2], 32), s3 = __shfl_xor(pk[3], 32);
      unsigned s4 = __shfl_xor(pk[4], 32), s5 = __shfl_xor(pk[5], 32);
      unsigned s6 = __shfl_xor(pk[6], 32), s7 = __shfl_xor(pk[7], 32);
      A10.u[0] = lhalf ? s2 : pk[0];
      A10.u[1] = lhalf ? s3 : pk[1];
      A10.u[2] = lhalf ? pk[2] : s0;
      A10.u[3] = lhalf ? pk[3] : s1;
      A11.u[0] = lhalf ? s6 : pk[4];
      A11.u[1] = lhalf ? s7 : pk[5];
      A11.u[2] = lhalf ? pk[6] : s4;
      A11.u[3] = lhalf ? pk[7] : s5;
    }

    // ---- stage E: PV(1) ----
    #pragma unroll
    for (int kstep = 0; kstep < 2; ++kstep) {
      f16x8 pf = kstep ? A11.v : A10.v;
      f16x8 v0 = __builtin_bit_cast(f16x8, sub1[512 + kstep * 256 +   0 + lane]);
      f16x8 v1 = __builtin_bit_cast(f16x8, sub1[512 + kstep * 256 +  64 + lane]);
      f16x8 v2 = __builtin_bit_cast(f16x8, sub1[512 + kstep * 256 + 128 + lane]);
      f16x8 v3 = __builtin_bit_cast(f16x8, sub1[512 + kstep * 256 + 192 + lane]);
      O0 = __builtin_amdgcn_mfma_f32_32x32x16_f16(pf, v0, O0, 0, 0, 0);
      O1 = __builtin_amdgcn_mfma_f32_32x32x16_f16(pf, v1, O1, 0, 0, 0);
      O2 = __builtin_amdgcn_mfma_f32_32x32x16_f16(pf, v2, O2, 0, 0, 0);
      O3 = __builtin_amdgcn_mfma_f32_32x32x16_f16(pf, v3, O3, 0, 0, 0);
    }
  }

  // ---- epilogue ----
  lsum += __shfl_xor(lsum, 32);           // combine the two key-halves

  if (PARTIAL) {
    if (lhalf == 0) ws_l[ks * S_LEN + qw + lrow] = lsum;   // plain store
    float* obase = (ks == 0) ? out
                 : (float*)(ws + PART_OFF) + (size_t)(ks - 1) * S_LEN * D_K;
    #pragma unroll
    for (int r = 0; r < 16; ++r) {
      int row = (r & 3) + 8 * (r >> 2) + 4 * lhalf;
      float* dst = obase + (size_t)(qw + row) * D_K + lrow;
      dst[ 0] = O0[r];
      dst[32] = O1[r];
      dst[64] = O2[r];
      dst[96] = O3[r];
    }
  } else {
    if (lhalf == 0) atomicAdd(ws_l + qw + lrow, lsum);
    #pragma unroll
    for (int r = 0; r < 16; ++r) {
      int row = (r & 3) + 8 * (r >> 2) + 4 * lhalf;
      float* dst = out + (size_t)(qw + row) * D_K + lrow;
      atomicAdd(dst +  0, O0[r]);
      atomicAdd(dst + 32, O1[r]);
      atomicAdd(dst + 64, O2[r]);
      atomicAdd(dst + 96, O3[r]);
    }
  }
}

// ---------------- reduce partials (nparts>0) or just normalize (nparts=0) ----
__global__ __launch_bounds__(256) void attn_norm(float* __restrict__ out,
                                                 const float* __restrict__ lpart,
                                                 const float* __restrict__ opart,
                                                 int nparts) {
  int i = blockIdx.x * 256 + threadIdx.x;  // float4 index, 262144 total
  int q = i >> 5;
  float4* o4 = (float4*)out;
  float4 acc = o4[i];
  float l = lpart[q];
  for (int s = 1; s <= nparts; ++s) {
    float4 p = ((const float4*)opart)[(size_t)(s - 1) * 262144 + i];
    acc.x += p.x; acc.y += p.y; acc.z += p.z; acc.w += p.w;
    l += lpart[s * S_LEN + q];
  }
  float inv = 1.0f / l;
  acc.x *= inv; acc.y *= inv; acc.z *= inv; acc.w *= inv;
  o4[i] = acc;
}

extern "C" void kernel_launch(void* const* d_in, const int* in_sizes, int n_in,
                              void* d_out, int out_size, void* d_ws, size_t ws_size,
                              hipStream_t stream) {
  const float* q = (const float*)d_in[0];
  const float* k = (const float*)d_in[1];
  const float* v = (const float*)d_in[2];
  float* out = (float*)d_out;
  char* ws = (char*)d_ws;

  if (ws_size >= WS_NEED) {
    attn_prep<false><<<dim3(512), dim3(512), 0, stream>>>(k, v, out, ws);
    attn_main<true><<<dim3(512), dim3(256), 0, stream>>>(q, out, ws);
    attn_norm<<<dim3(1024), dim3(256), 0, stream>>>(
        out, (const float*)(ws + WS_L_OFF), (const float*)(ws + PART_OFF), 7);
  } else {
    attn_prep<true><<<dim3(645), dim3(512), 0, stream>>>(k, v, out, ws);
    attn_main<false><<<dim3(512), dim3(256), 0, stream>>>(q, out, ws);
    attn_norm<<<dim3(1024), dim3(256), 0, stream>>>(
        out, (const float*)(ws + WS_L_OFF), (const float*)(ws + PART_OFF), 0);
  }
}